// Round 10
// baseline (215.306 us; speedup 1.0000x reference)
//
#include <hip/hip_runtime.h>
#include <hip/hip_bf16.h>
#include <stdint.h>

#define Bb 128
#define Pp 4096
#define Ff 32
#define Kk 8
#define Dd 64
#define ROUNDS 2
#define NSLICE 32   // 8 (grid.y) * 4 waves

constexpr float EPS_ATTN_ = 1e-8f;
constexpr float EPS_LN_   = 1e-5f;
constexpr float SCALE_    = 0.125f;  // 64^-0.5

typedef __attribute__((ext_vector_type(8))) short short8;
typedef __attribute__((ext_vector_type(4))) float floatx4;

__device__ __forceinline__ unsigned short f2bf(float f) {
  union { float f; unsigned u; } c; c.f = f;
  unsigned u = c.u + 0x7fffu + ((c.u >> 16) & 1u);  // RNE
  return (unsigned short)(u >> 16);
}
__device__ __forceinline__ float bf2f(unsigned h) {
  union { float f; unsigned u; } c; c.u = h << 16;
  return c.f;
}
__device__ __forceinline__ unsigned pkbf(float a, float b) {
  __hip_bfloat162 h2 = __float22bfloat162_rn(make_float2(a, b));
  union { __hip_bfloat162 h; unsigned u; } c; c.h = h2;
  return c.u;
}
__device__ __forceinline__ float wsum(float v) {
  v += __shfl_xor(v, 1, 64);  v += __shfl_xor(v, 2, 64);
  v += __shfl_xor(v, 4, 64);  v += __shfl_xor(v, 8, 64);
  v += __shfl_xor(v, 16, 64); v += __shfl_xor(v, 32, 64);
  return v;
}

// ---------------------------------------------------------------------------
// fattn: grid (128,8) x 256 thr, LDS 40960 B -> 4 blocks/CU (one uniform pass).
// r9 lesson: A_lds stride 72->64 made row-stride = 0 mod 64 banks -> phase-2
// af b128 read 8-way conflicted (SQ_LDS_BANK_CONFLICT 475K->2.5M). Fix:
// XOR swizzle col ^= (row&7)<<3 (bijective per row; 8-aligned spans intact).
// NEW: fattn1 stores LN'd bf16 x (xn, 32MB ws); fattn2 loads xn and skips
// the whole LN+shuffle chain (bit-identical bf16 values -> numerics unchanged).
// LDS map:
//  [0..20480)     xb : bf16 LN'd x pixel-major [256][40]
//  [20480..36864) xbT: bf16 LN'd x f-major     [32][256]  (XOR-swizzled)
//  [36864..40960) A_lds [4][8][64]                         (XOR-swizzled)
//  iter-1 preamble aliases [0..28160): wq@0 wk@16640 lnv@25088 qtb@27136
// Round loop: zero barriers (all LDS wave-private; r4-verified).
// ---------------------------------------------------------------------------
template <bool ITER2>
__global__ __launch_bounds__(256, 4) void fattn_kernel(
    const float* __restrict__ x, const unsigned short* __restrict__ qt_bf,
    const float* __restrict__ lg, const float* __restrict__ lb,
    const float* __restrict__ noise, const float* __restrict__ smu,
    const float* __restrict__ ssig, const float* __restrict__ Wq,
    const float* __restrict__ Wk, const float* __restrict__ lsg,
    const float* __restrict__ lsb,
    float* __restrict__ acc_tp, float* __restrict__ Ssp,
    unsigned short* __restrict__ attn_bf, unsigned short* __restrict__ xn) {
  const int b    = blockIdx.x;
  const int yb   = blockIdx.y;
  const int w    = threadIdx.x >> 6;
  const int lane = threadIdx.x & 63;
  const int m    = lane & 15;
  const int quad = lane >> 4;
  const int c    = (lane & 7) * 4;       // this lane's feature-quad base
  __shared__ __align__(16) char smem[40960];
  unsigned short* xb  = (unsigned short*)smem;
  unsigned short* xbT = (unsigned short*)(smem + 20480);
  unsigned short (*A_lds)[8][64] = (unsigned short (*)[8][64])(smem + 36864);

  const float4* xg4 =
      (const float4*)x + ((size_t)b * Pp + (size_t)yb * (ROUNDS * 256)) * 8;
  unsigned short* xnb =
      xn + ((size_t)b * Pp + (size_t)yb * (ROUNDS * 256)) * 32;
  float4 st[8];    // !ITER2: raw f32 x (coalesced)
  uint2  st2[8];   //  ITER2: LN'd bf16 xn (coalesced)
  if (!ITER2) {
    #pragma unroll
    for (int i = 0; i < 8; ++i)
      st[i] = xg4[w * 512 + i * 64 + lane];
  } else {
    #pragma unroll
    for (int i = 0; i < 8; ++i)
      st2[i] = *(const uint2*)&xnb[(size_t)(w * 64 + i * 8 + (lane >> 3)) * 32 + c];
  }

  // LN gain/bias for this lane's 4 columns (iter-1 only)
  float4 lgv, lbv;
  if (!ITER2) {
    lgv = *(const float4*)&lg[c];
    lbv = *(const float4*)&lb[c];
  }

  short8 aq;
  if (!ITER2) {
    // ---- per-block q~ preamble (iter 1) ----
    float* wq  = (float*)smem;             // 64*65
    float* wk  = (float*)(smem + 16640);   // 64*33
    float* lnv = (float*)(smem + 25088);   // 8*64
    unsigned short* qtb = (unsigned short*)(smem + 27136);  // 16*32
    {
      const float4* g4 = (const float4*)Wq;
      #pragma unroll
      for (int i = 0; i < 4; ++i) {
        int f4i = threadIdx.x + i * 256;
        float4 v = g4[f4i];
        int fi = f4i * 4, row = fi >> 6, col = fi & 63;
        float* dst = &wq[row * 65 + col];
        dst[0] = v.x; dst[1] = v.y; dst[2] = v.z; dst[3] = v.w;
      }
      const float4* gk = (const float4*)Wk;
      #pragma unroll
      for (int i = 0; i < 2; ++i) {
        int f4i = threadIdx.x + i * 256;
        float4 v = gk[f4i];
        int fi = f4i * 4, row = fi >> 5, col = fi & 31;
        float* dst = &wk[row * 33 + col];
        dst[0] = v.x; dst[1] = v.y; dst[2] = v.z; dst[3] = v.w;
      }
    }
    const int j = lane;
    #pragma unroll
    for (int kk0 = 0; kk0 < 2; ++kk0) {
      const int kk = w + kk0 * 4;
      float s0 = smu[j] + fabsf(ssig[j]) * noise[((size_t)b * Kk + kk) * Dd + j];
      float mu  = wsum(s0) * (1.f / 64.f);
      float dc  = s0 - mu;
      float var = wsum(dc * dc) * (1.f / 64.f);
      lnv[kk * 64 + j] = dc * rsqrtf(var + EPS_LN_) * lsg[j] + lsb[j];
    }
    __syncthreads();
    float qa = 0.f, qb = 0.f;
    #pragma unroll 8
    for (int d = 0; d < Dd; ++d) {
      float wv = wq[j * 65 + d];
      qa = fmaf(wv, lnv[w * 64 + d],       qa);
      qb = fmaf(wv, lnv[(w + 4) * 64 + d], qb);
    }
    __syncthreads();
    lnv[w * 64 + j]       = qa * SCALE_;
    lnv[(w + 4) * 64 + j] = qb * SCALE_;
    __syncthreads();
    {
      const int kq = threadIdx.x >> 5, fq = threadIdx.x & 31;
      float qt = 0.f;
      #pragma unroll 8
      for (int d = 0; d < Dd; ++d) qt = fmaf(lnv[kq * 64 + d], wk[d * 33 + fq], qt);
      qtb[kq * 32 + fq]       = f2bf(qt);
      qtb[(kq + 8) * 32 + fq] = 0;           // zero rows 8..15 (MFMA M=16)
    }
    __syncthreads();
    aq = *(const short8*)&qtb[m * 32 + quad * 8];
    __syncthreads();   // qtb/lnv reads done before xb/xbT writes overwrite
  } else {
    aq = *(const short8*)(qt_bf + ((size_t)b * 16 + m) * Ff + quad * 8);
  }

  float Ss0 = 0.f, Ss1 = 0.f, Ss2 = 0.f, Ss3 = 0.f;
  floatx4 Cg0 = {0.f,0.f,0.f,0.f}, Cg1 = {0.f,0.f,0.f,0.f};

  #pragma unroll 1
  for (int rr = 0; rr < ROUNDS; ++rr) {
    // ---- produce/consume LN'd bf16 pixels; write xb/xbT (wave-private)
    #pragma unroll
    for (int i = 0; i < 8; ++i) {
      const int pxl = w * 64 + i * 8 + (lane >> 3);   // own pixel, own wave
      unsigned u0, u1;
      if (!ITER2) {
        float4 v = st[i];
        if (rr + 1 < ROUNDS)   // rotate prefetch into the just-freed slot
          st[i] = xg4[(rr + 1) * 2048 + w * 512 + i * 64 + lane];
        float s = (v.x + v.y) + (v.z + v.w);
        s += __shfl_xor(s, 1, 64);
        s += __shfl_xor(s, 2, 64);
        s += __shfl_xor(s, 4, 64);
        const float mu = s * (1.f / 32.f);
        const float d0 = v.x - mu, d1 = v.y - mu, d2 = v.z - mu, d3 = v.w - mu;
        float q = fmaf(d0, d0, fmaf(d1, d1, fmaf(d2, d2, d3 * d3)));
        q += __shfl_xor(q, 1, 64);
        q += __shfl_xor(q, 2, 64);
        q += __shfl_xor(q, 4, 64);
        const float rn = rsqrtf(q * (1.f / 32.f) + EPS_LN_);
        const float o0 = fmaf(d0 * rn, lgv.x, lbv.x);
        const float o1 = fmaf(d1 * rn, lgv.y, lbv.y);
        const float o2 = fmaf(d2 * rn, lgv.z, lbv.z);
        const float o3 = fmaf(d3 * rn, lgv.w, lbv.w);
        u0 = pkbf(o0, o1); u1 = pkbf(o2, o3);
        // persist LN'd bf16 x for iter-2 reuse (coalesced 512B/wave)
        *(uint2*)&xnb[(size_t)(rr * 256 + pxl) * 32 + c] = make_uint2(u0, u1);
      } else {
        uint2 uv = st2[i];
        if (rr + 1 < ROUNDS)
          st2[i] = *(const uint2*)&xnb[(size_t)((rr + 1) * 256 + pxl) * 32 + c];
        u0 = uv.x; u1 = uv.y;
      }
      *(uint2*)&xb[pxl * 40 + c] = make_uint2(u0, u1);
      // XOR-swizzled f-major store: col = px ^ ((f&7)<<3)
      xbT[(c + 0) * 256 + (pxl ^ (((c + 0) & 7) << 3))] = (unsigned short)(u0 & 0xffffu);
      xbT[(c + 1) * 256 + (pxl ^ (((c + 1) & 7) << 3))] = (unsigned short)(u0 >> 16);
      xbT[(c + 2) * 256 + (pxl ^ (((c + 2) & 7) << 3))] = (unsigned short)(u1 & 0xffffu);
      xbT[(c + 3) * 256 + (pxl ^ (((c + 3) & 7) << 3))] = (unsigned short)(u1 >> 16);
    }

    // ---- phase 1: dots + softmax over slots (reads wave-own xb rows)
    const int p0 = yb * (ROUNDS * 256) + rr * 256;
    #pragma unroll
    for (int t = 0; t < 4; ++t) {
      const int lpx = w * 64 + t * 16 + m;
      const short8 bx = *(const short8*)&xb[lpx * 40 + quad * 8];
      floatx4 C = {0.f, 0.f, 0.f, 0.f};
      C = __builtin_amdgcn_mfma_f32_16x16x32_bf16(aq, bx, C, 0, 0, 0);
      // C: col=m=pixel, row=quad*4+r=slot; slot pairs in lanes {l, l^16}
      float mx = fmaxf(fmaxf(C[0], C[1]), fmaxf(C[2], C[3]));
      mx = fmaxf(mx, __shfl_xor(mx, 16, 64));
      float e0 = __expf(C[0] - mx), e1 = __expf(C[1] - mx),
            e2 = __expf(C[2] - mx), e3 = __expf(C[3] - mx);
      float s = e0 + e1 + e2 + e3;
      s += __shfl_xor(s, 16, 64);
      float inv = 1.f / s;
      float a0 = fmaf(e0, inv, EPS_ATTN_), a1 = fmaf(e1, inv, EPS_ATTN_);
      float a2 = fmaf(e2, inv, EPS_ATTN_), a3 = fmaf(e3, inv, EPS_ATTN_);
      Ss0 += a0; Ss1 += a1; Ss2 += a2; Ss3 += a3;
      if (quad < 2) {                      // rows 0..7 are the real slots
        const int r0 = quad * 4;
        unsigned c01 = pkbf(a0, a1), c23 = pkbf(a2, a3);
        const int col = t * 16 + m;
        // A_lds XOR-swizzled: col ^ (row<<3)  (rows spread across banks)
        A_lds[w][r0 + 0][col ^ ((r0 + 0) << 3)] = (unsigned short)(c01 & 0xffffu);
        A_lds[w][r0 + 1][col ^ ((r0 + 1) << 3)] = (unsigned short)(c01 >> 16);
        A_lds[w][r0 + 2][col ^ ((r0 + 2) << 3)] = (unsigned short)(c23 & 0xffffu);
        A_lds[w][r0 + 3][col ^ ((r0 + 3) << 3)] = (unsigned short)(c23 >> 16);
      }
    }
    // ---- phase 2: acc[slot][f] += attn @ xn (reads wave-own A_lds/xbT)
    #pragma unroll
    for (int ks = 0; ks < 2; ++ks) {
      const int acol = (ks * 32 + quad * 8) ^ ((m & 7) << 3);  // A_lds swizzle
      const short8 af = *(const short8*)(&A_lds[w][m & 7][acol]);
      const int pxo = (w * 64 + ks * 32 + quad * 8) ^ ((m & 7) << 3);
      const short8 xg0 = *(const short8*)&xbT[(m)      * 256 + pxo];  // f = m
      const short8 xg1 = *(const short8*)&xbT[(16 + m) * 256 + pxo];  // f = 16+m
      Cg0 = __builtin_amdgcn_mfma_f32_16x16x32_bf16(af, xg0, Cg0, 0, 0, 0);
      Cg1 = __builtin_amdgcn_mfma_f32_16x16x32_bf16(af, xg1, Cg1, 0, 0, 0);
    }
    // ---- iter-2: coalesced dump of this round's unnormalized attn (bf16)
    if (ITER2) {
      const int sl = lane >> 3, p8 = (lane & 7) * 8;
      const short8 av = *(const short8*)&A_lds[w][sl][p8 ^ (sl << 3)];
      *(short8*)(attn_bf + ((size_t)b * Kk + sl) * Pp + p0 + w * 64 + p8) = av;
    }
  }
  // ---- epilogue: per-wave private slices (slice id = yb*4 + w, 32 total)
  Ss0 += __shfl_xor(Ss0,1,64); Ss0 += __shfl_xor(Ss0,2,64); Ss0 += __shfl_xor(Ss0,4,64); Ss0 += __shfl_xor(Ss0,8,64);
  Ss1 += __shfl_xor(Ss1,1,64); Ss1 += __shfl_xor(Ss1,2,64); Ss1 += __shfl_xor(Ss1,4,64); Ss1 += __shfl_xor(Ss1,8,64);
  Ss2 += __shfl_xor(Ss2,1,64); Ss2 += __shfl_xor(Ss2,2,64); Ss2 += __shfl_xor(Ss2,4,64); Ss2 += __shfl_xor(Ss2,8,64);
  Ss3 += __shfl_xor(Ss3,1,64); Ss3 += __shfl_xor(Ss3,2,64); Ss3 += __shfl_xor(Ss3,4,64); Ss3 += __shfl_xor(Ss3,8,64);
  if (quad < 2) {
    const int row = quad * 4;
    const int slice = yb * 4 + w;            // 0..31
    float* tp = acc_tp + (size_t)b * (NSLICE * 256) + (size_t)slice * 256 +
                (size_t)row * 32 + m;
    #pragma unroll
    for (int r = 0; r < 4; ++r) {
      tp[r * 32]      = Cg0[r];
      tp[r * 32 + 16] = Cg1[r];
    }
    if (m == 0) {
      float* sp = Ssp + ((size_t)b * NSLICE + slice) * 8 + row;
      sp[0] = Ss0; sp[1] = Ss1; sp[2] = Ss2; sp[3] = Ss3;
    }
  }
}

__device__ __forceinline__ void stage_gate_pair(
    float* A, float* Bd, const float* Wih, const float* Whh, int g) {
  const float4* gi = (const float4*)Wih + (size_t)g * 1024;  // rows [64g,64g+64)
  const float4* gh = (const float4*)Whh + (size_t)g * 1024;
  #pragma unroll
  for (int i = 0; i < 4; ++i) {
    int f4i = threadIdx.x + i * 256;
    float4 vi = gi[f4i], vh = gh[f4i];
    int fi = f4i * 4, row = fi >> 6, col = fi & 63;
    float* da = &A[row * 65 + col];
    float* db = &Bd[row * 65 + col];
    da[0]=vi.x; da[1]=vi.y; da[2]=vi.z; da[3]=vi.w;
    db[0]=vh.x; db[1]=vh.y; db[2]=vh.z; db[3]=vh.w;
  }
}

// gru phase (device fn): weights staged sequentially per gate, 37376 B LDS.
// Verified correct in rounds 2-9.
template <bool LAST>
__device__ void gru_phase(
    char* smem,
    const float* __restrict__ acc_tp, const float* __restrict__ Ssp,
    float* __restrict__ slots,
    const float* __restrict__ noise, const float* __restrict__ smu,
    const float* __restrict__ ssig,
    const float* __restrict__ W_ih, const float* __restrict__ W_hh,
    const float* __restrict__ b_ih, const float* __restrict__ b_hh,
    const float* __restrict__ fg, const float* __restrict__ fb,
    const float* __restrict__ W1, const float* __restrict__ b1,
    const float* __restrict__ W2, const float* __restrict__ b2,
    const float* __restrict__ lsg, const float* __restrict__ lsb,
    const float* __restrict__ Wq, const float* __restrict__ Wv,
    const float* __restrict__ Wk,
    unsigned short* __restrict__ qt_bf, float* __restrict__ out_slots) {
  const int b  = blockIdx.x;
  const int kh = blockIdx.y;              // 0..1, slot half
  const int k  = threadIdx.x >> 6;        // local slot 0..3
  const int j  = threadIdx.x & 63;
  const int kg = kh * 4 + k;
  const size_t rk = (size_t)b * Kk + kg;
  float* WS0 = (float*)smem;              // staging (<= 33280 B)
  float* At  = (float*)(smem + 16640);    // C1 only
  float* WS1 = (float*)(smem + 16640);
  float* qs  = (float*)(smem + 16640);    // C7 only
  float* WKs = (float*)(smem + 17664);    // C7 only
  float* Ub  = (float*)(smem + 33280);    // [4][64]
  float* Hb  = (float*)(smem + 34304);    // [4][64]
  float* Tb  = (float*)(smem + 35328);    // [4][128], ends 37376

  // ---- C1: Wv stage; S & At sums; h; u = (T @ Wv^T)/S
  {
    const float4* gv = (const float4*)Wv;
    #pragma unroll
    for (int i = 0; i < 2; ++i) {
      int f4i = threadIdx.x + i * 256;
      float4 v = gv[f4i];
      int fi = f4i * 4, row = fi >> 5, col = fi & 31;
      float* d_ = &WS0[row * 33 + col];
      d_[0]=v.x; d_[1]=v.y; d_[2]=v.z; d_[3]=v.w;
    }
  }
  float S = 0.f;
  #pragma unroll
  for (int y2 = 0; y2 < NSLICE; ++y2) S += Ssp[((size_t)b * NSLICE + y2) * 8 + kg];
  if (j < Ff) {
    const float* tp = acc_tp + (size_t)b * (NSLICE * 256) + (size_t)kg * 32 + j;
    float t = 0.f;
    #pragma unroll
    for (int y2 = 0; y2 < NSLICE; ++y2) t += tp[y2 * 256];
    At[k * Ff + j] = t;
  }
  float h;
  if (LAST) h = slots[rk * Dd + j];
  else      h = smu[j] + fabsf(ssig[j]) * noise[rk * Dd + j];  // slots0
  Hb[k * Dd + j] = h;
  __syncthreads();
  float u = 0.f;
  #pragma unroll 8
  for (int f = 0; f < Ff; ++f) u = fmaf(WS0[j * 33 + f], At[k * Ff + f], u);
  u /= S;
  Ub[k * Dd + j] = u;
  __syncthreads();

  // ---- C2..C4: gates r,z,n staged one at a time
  float gr, hr, gz, hz, gn, hn_;
  stage_gate_pair(WS0, WS1, W_ih, W_hh, 0);
  __syncthreads();
  gr = b_ih[j]; hr = b_hh[j];
  #pragma unroll 4
  for (int d = 0; d < Dd; ++d) {
    gr = fmaf(WS0[j * 65 + d], Ub[k * Dd + d], gr);
    hr = fmaf(WS1[j * 65 + d], Hb[k * Dd + d], hr);
  }
  __syncthreads();
  stage_gate_pair(WS0, WS1, W_ih, W_hh, 1);
  __syncthreads();
  gz = b_ih[64 + j]; hz = b_hh[64 + j];
  #pragma unroll 4
  for (int d = 0; d < Dd; ++d) {
    gz = fmaf(WS0[j * 65 + d], Ub[k * Dd + d], gz);
    hz = fmaf(WS1[j * 65 + d], Hb[k * Dd + d], hz);
  }
  __syncthreads();
  stage_gate_pair(WS0, WS1, W_ih, W_hh, 2);
  __syncthreads();
  gn = b_ih[128 + j]; hn_ = b_hh[128 + j];
  #pragma unroll 4
  for (int d = 0; d < Dd; ++d) {
    gn  = fmaf(WS0[j * 65 + d], Ub[k * Dd + d], gn);
    hn_ = fmaf(WS1[j * 65 + d], Hb[k * Dd + d], hn_);
  }
  const float r = 1.f / (1.f + __expf(-(gr + hr)));
  const float z = 1.f / (1.f + __expf(-(gz + hz)));
  const float n = tanhf(fmaf(r, hn_, gn));
  const float hnew = fmaf(z, h - n, n);    // (1-z)*n + z*h
  float mu  = wsum(hnew) * (1.f / 64.f);
  float dc  = hnew - mu;
  float var = wsum(dc * dc) * (1.f / 64.f);
  float fi_ = dc * rsqrtf(var + EPS_LN_) * fg[j] + fb[j];
  __syncthreads();   // all gate reads of WS0/WS1/Ub done
  Ub[k * Dd + j] = fi_;
  // ---- C5: W1 (128x65)
  {
    const float4* g1 = (const float4*)W1;
    #pragma unroll
    for (int i = 0; i < 8; ++i) {
      int f4i = threadIdx.x + i * 256;
      float4 v = g1[f4i];
      int fi = f4i * 4, row = fi >> 6, col = fi & 63;
      float* d_ = &WS0[row * 65 + col];
      d_[0]=v.x; d_[1]=v.y; d_[2]=v.z; d_[3]=v.w;
    }
  }
  __syncthreads();
  float f1a = b1[j], f1b = b1[64 + j];
  #pragma unroll 4
  for (int d = 0; d < Dd; ++d) {
    const float t = Ub[k * Dd + d];
    f1a = fmaf(WS0[j * 65 + d],        t, f1a);
    f1b = fmaf(WS0[(64 + j) * 65 + d], t, f1b);
  }
  f1a = fmaxf(f1a, 0.f);
  f1b = fmaxf(f1b, 0.f);
  Tb[k * 128 + j]      = f1a;
  Tb[k * 128 + 64 + j] = f1b;
  __syncthreads();
  // ---- C6: W2 (64x129)
  {
    const float4* g2 = (const float4*)W2;
    #pragma unroll
    for (int i = 0; i < 8; ++i) {
      int f4i = threadIdx.x + i * 256;
      float4 v = g2[f4i];
      int fi = f4i * 4, row = fi >> 7, col = fi & 127;
      float* d_ = &WS0[row * 129 + col];
      d_[0]=v.x; d_[1]=v.y; d_[2]=v.z; d_[3]=v.w;
    }
  }
  __syncthreads();
  float o = b2[j];
  #pragma unroll 4
  for (int e = 0; e < 2 * Dd; ++e) o = fmaf(WS0[j * 129 + e], Tb[k * 128 + e], o);
  const float sn = hnew + o;
  if (!LAST) {
    slots[rk * Dd + j] = sn;
    float mq = wsum(sn) * (1.f / 64.f);
    float dq = sn - mq;
    float vq = wsum(dq * dq) * (1.f / 64.f);
    float xq = dq * rsqrtf(vq + EPS_LN_) * lsg[j] + lsb[j];
    __syncthreads();          // W2/Tb reads done before restage / Ub rewrite
    Ub[k * Dd + j] = xq;
    // ---- C7: Wq + Wk -> q~ for iter 2
    {
      const float4* gq = (const float4*)Wq;
      #pragma unroll
      for (int i = 0; i < 4; ++i) {
        int f4i = threadIdx.x + i * 256;
        float4 v = gq[f4i];
        int fi = f4i * 4, row = fi >> 6, col = fi & 63;
        float* d_ = &WS0[row * 65 + col];
        d_[0]=v.x; d_[1]=v.y; d_[2]=v.z; d_[3]=v.w;
      }
      const float4* gk2 = (const float4*)Wk;
      #pragma unroll
      for (int i = 0; i < 2; ++i) {
        int f4i = threadIdx.x + i * 256;
        float4 v = gk2[f4i];
        int fi = f4i * 4, row = fi >> 5, col = fi & 31;
        float* d_ = &WKs[row * 33 + col];
        d_[0]=v.x; d_[1]=v.y; d_[2]=v.z; d_[3]=v.w;
      }
    }
    __syncthreads();
    float q = 0.f;
    #pragma unroll 8
    for (int d = 0; d < Dd; ++d) q = fmaf(WS0[j * 65 + d], Ub[k * Dd + d], q);
    qs[k * Dd + j] = q * SCALE_;
    __syncthreads();
    if (j < Ff) {
      float qt = 0.f;
      #pragma unroll 8
      for (int d = 0; d < Dd; ++d) qt = fmaf(qs[k * Dd + d], WKs[d * 33 + j], qt);
      qt_bf[((size_t)b * 16 + kg) * Ff + j]     = f2bf(qt);
      qt_bf[((size_t)b * 16 + kg + 8) * Ff + j] = 0;
    }
  } else {
    out_slots[rk * Dd + j] = sn;
  }
}

__global__ __launch_bounds__(256) void gru1_kernel(
    const float* __restrict__ acc_tp, const float* __restrict__ Ssp,
    float* __restrict__ slots,
    const float* __restrict__ noise, const float* __restrict__ smu,
    const float* __restrict__ ssig,
    const float* __restrict__ W_ih, const float* __restrict__ W_hh,
    const float* __restrict__ b_ih, const float* __restrict__ b_hh,
    const float* __restrict__ fg, const float* __restrict__ fb,
    const float* __restrict__ W1, const float* __restrict__ b1,
    const float* __restrict__ W2, const float* __restrict__ b2,
    const float* __restrict__ lsg, const float* __restrict__ lsb,
    const float* __restrict__ Wq, const float* __restrict__ Wv,
    const float* __restrict__ Wk, unsigned short* __restrict__ qt_bf) {
  __shared__ __align__(16) char smem[37376];
  gru_phase<false>(smem, acc_tp, Ssp, slots, noise, smu, ssig, W_ih, W_hh,
                   b_ih, b_hh, fg, fb, W1, b1, W2, b2, lsg, lsb, Wq, Wv, Wk,
                   qt_bf, nullptr);
}

// grid (128,18): yb<2 -> gru iter2 (-> out_slots); yb in [2,18) -> normalize
// strip (yb-2) of out_attn (256 px x 8 slots) from bf16 attn_bf and 1/S.
__global__ __launch_bounds__(256) void gru2_scale_kernel(
    const float* __restrict__ acc_tp, const float* __restrict__ Ssp,
    float* __restrict__ slots,
    const float* __restrict__ noise, const float* __restrict__ smu,
    const float* __restrict__ ssig,
    const float* __restrict__ W_ih, const float* __restrict__ W_hh,
    const float* __restrict__ b_ih, const float* __restrict__ b_hh,
    const float* __restrict__ fg, const float* __restrict__ fb,
    const float* __restrict__ W1, const float* __restrict__ b1,
    const float* __restrict__ W2, const float* __restrict__ b2,
    const float* __restrict__ lsg, const float* __restrict__ lsb,
    const float* __restrict__ Wq, const float* __restrict__ Wv,
    const float* __restrict__ Wk,
    const unsigned short* __restrict__ attn_bf,
    float* __restrict__ out_slots, float* __restrict__ out_attn) {
  __shared__ __align__(16) char smem[37376];
  if (blockIdx.y < 2) {
    gru_phase<true>(smem, acc_tp, Ssp, slots, noise, smu, ssig, W_ih, W_hh,
                    b_ih, b_hh, fg, fb, W1, b1, W2, b2, lsg, lsb, Wq, Wv, Wk,
                    nullptr, out_slots);
  } else {
    const int b = blockIdx.x;
    const int s = blockIdx.y - 2;           // strip 0..15 (256 px each)
    float* Sbuf = (float*)smem;
    if (threadIdx.x < 8) {
      float S = 0.f;
      #pragma unroll
      for (int y2 = 0; y2 < NSLICE; ++y2)
        S += Ssp[((size_t)b * NSLICE + y2) * 8 + threadIdx.x];
      Sbuf[threadIdx.x] = 1.f / S;
    }
    __syncthreads();
    #pragma unroll
    for (int i = 0; i < 2; ++i) {
      int g = threadIdx.x + i * 256;        // 0..511
      int slot = g >> 6;                    // 0..7
      int px4 = (g & 63) * 4;               // 0..252
      size_t off = ((size_t)b * Kk + slot) * Pp + (size_t)s * 256 + px4;
      uint2 v = *(const uint2*)(attn_bf + off);
      float inv = Sbuf[slot];
      float4 ov;
      ov.x = bf2f(v.x & 0xffffu) * inv;
      ov.y = bf2f(v.x >> 16)     * inv;
      ov.z = bf2f(v.y & 0xffffu) * inv;
      ov.w = bf2f(v.y >> 16)     * inv;
      *(float4*)(out_attn + off) = ov;
    }
  }
}

extern "C" void kernel_launch(void* const* d_in, const int* in_sizes, int n_in,
                              void* d_out, int out_size, void* d_ws, size_t ws_size,
                              hipStream_t stream) {
  const float* x      = (const float*)d_in[0];
  const float* noise  = (const float*)d_in[1];
  const float* smu    = (const float*)d_in[2];
  const float* ssig   = (const float*)d_in[3];
  const float* Wq     = (const float*)d_in[4];
  const float* Wk     = (const float*)d_in[5];
  const float* Wv     = (const float*)d_in[6];
  const float* W_ih   = (const float*)d_in[7];
  const float* W_hh   = (const float*)d_in[8];
  const float* b_ih   = (const float*)d_in[9];
  const float* b_hh   = (const float*)d_in[10];
  const float* ln_in_g = (const float*)d_in[11];
  const float* ln_in_b = (const float*)d_in[12];
  const float* ln_s_g  = (const float*)d_in[13];
  const float* ln_s_b  = (const float*)d_in[14];
  const float* ff_g   = (const float*)d_in[15];
  const float* ff_b   = (const float*)d_in[16];
  const float* W1     = (const float*)d_in[17];
  const float* b1     = (const float*)d_in[18];
  const float* W2     = (const float*)d_in[19];
  const float* b2     = (const float*)d_in[20];

  char* ws = (char*)d_ws;
  unsigned short* qt_bf = (unsigned short*)(ws);             //    131,072 B
  float* slots   = (float*)(ws + 131072);                    //    262,144 B
  float* acc_tp  = (float*)(ws + 393216);                    //  4,194,304 B [B][32][8][32]
  float* Ssp     = (float*)(ws + 4587520);                   //    131,072 B [B][32][8]
  unsigned short* attn_bf = (unsigned short*)(ws + 4718592); //  8,388,608 B [B][K][P]
  unsigned short* xn      = (unsigned short*)(ws + 13107200);// 33,554,432 B [B][P][F] bf16

  float* out_slots = (float*)d_out;                          // [B,K,D] f32
  float* out_attn  = out_slots + (size_t)Bb * Kk * Dd;       // [B,K,P] f32

  fattn_kernel<false><<<dim3(Bb, 8), dim3(256), 0, stream>>>(
      x, nullptr, ln_in_g, ln_in_b, noise, smu, ssig, Wq, Wk, ln_s_g, ln_s_b,
      acc_tp, Ssp, nullptr, xn);
  gru1_kernel<<<dim3(Bb, 2), dim3(256), 0, stream>>>(
      acc_tp, Ssp, slots, noise, smu, ssig, W_ih, W_hh, b_ih, b_hh, ff_g, ff_b,
      W1, b1, W2, b2, ln_s_g, ln_s_b, Wq, Wv, Wk, qt_bf);
  fattn_kernel<true><<<dim3(Bb, 8), dim3(256), 0, stream>>>(
      x, qt_bf, ln_in_g, ln_in_b, nullptr, nullptr, nullptr, nullptr, nullptr,
      nullptr, nullptr, acc_tp, Ssp, attn_bf, xn);
  gru2_scale_kernel<<<dim3(Bb, 18), dim3(256), 0, stream>>>(
      acc_tp, Ssp, slots, noise, smu, ssig, W_ih, W_hh, b_ih, b_hh, ff_g, ff_b,
      W1, b1, W2, b2, ln_s_g, ln_s_b, Wq, Wv, Wk, attn_bf, out_slots, out_attn);
}

// Round 11
// 196.206 us; speedup vs baseline: 1.0973x; 1.0973x over previous
//
#include <hip/hip_runtime.h>
#include <hip/hip_bf16.h>
#include <stdint.h>

#define Bb 128
#define Pp 4096
#define Ff 32
#define Kk 8
#define Dd 64
#define ROUNDS 2
#define NSLICE 32   // 8 (grid.y) * 4 waves

constexpr float EPS_ATTN_ = 1e-8f;
constexpr float EPS_LN_   = 1e-5f;
constexpr float SCALE_    = 0.125f;  // 64^-0.5

typedef __attribute__((ext_vector_type(8))) short short8;
typedef __attribute__((ext_vector_type(4))) float floatx4;

__device__ __forceinline__ unsigned short f2bf(float f) {
  union { float f; unsigned u; } c; c.f = f;
  unsigned u = c.u + 0x7fffu + ((c.u >> 16) & 1u);  // RNE
  return (unsigned short)(u >> 16);
}
__device__ __forceinline__ float bf2f(unsigned h) {
  union { float f; unsigned u; } c; c.u = h << 16;
  return c.f;
}
__device__ __forceinline__ unsigned pkbf(float a, float b) {
  __hip_bfloat162 h2 = __float22bfloat162_rn(make_float2(a, b));
  union { __hip_bfloat162 h; unsigned u; } c; c.h = h2;
  return c.u;
}
__device__ __forceinline__ float wsum(float v) {
  v += __shfl_xor(v, 1, 64);  v += __shfl_xor(v, 2, 64);
  v += __shfl_xor(v, 4, 64);  v += __shfl_xor(v, 8, 64);
  v += __shfl_xor(v, 16, 64); v += __shfl_xor(v, 32, 64);
  return v;
}

// ---------------------------------------------------------------------------
// fattn: grid (128,8) x 256 thr. REVERTED to the r8 configuration (best
// measured: 202.8us, conflicts 475K, no spill): LDS 41984 B -> 3 blocks/CU,
// xbT [32][264] UNswizzled (r10 lesson: swizzling broke the STORE side ->
// 8-way write conflict, 2.2M; [264]'s stride gives conflict-free stores AND
// +4-bank row offset on reads), A_lds [4][8][72].
// KEPT from r10: xn reuse -- fattn1 persists LN'd bf16 x (32MB ws);
// fattn2 loads xn directly in the round loop (no prefetch array, no LN
// chain -> LOWER reg pressure than r8; loads are LLC-warm). Bit-identical.
// LDS map:
//  [0..20480)     xb : bf16 LN'd x pixel-major [256][40]
//  [20480..37376) xbT: bf16 LN'd x f-major     [32][264]
//  [37376..41984) A_lds [4][8][72]
//  iter-1 preamble aliases [0..28160): wq@0 wk@16640 lnv@25088 qtb@27136
// Round loop: zero barriers (all LDS wave-private; r4-verified).
// ---------------------------------------------------------------------------
template <bool ITER2>
__global__ __launch_bounds__(256, 3) void fattn_kernel(
    const float* __restrict__ x, const unsigned short* __restrict__ qt_bf,
    const float* __restrict__ lg, const float* __restrict__ lb,
    const float* __restrict__ noise, const float* __restrict__ smu,
    const float* __restrict__ ssig, const float* __restrict__ Wq,
    const float* __restrict__ Wk, const float* __restrict__ lsg,
    const float* __restrict__ lsb,
    float* __restrict__ acc_tp, float* __restrict__ Ssp,
    unsigned short* __restrict__ attn_bf, unsigned short* __restrict__ xn) {
  const int b    = blockIdx.x;
  const int yb   = blockIdx.y;
  const int w    = threadIdx.x >> 6;
  const int lane = threadIdx.x & 63;
  const int m    = lane & 15;
  const int quad = lane >> 4;
  const int c    = (lane & 7) * 4;       // this lane's feature-quad base
  __shared__ __align__(16) char smem[41984];
  unsigned short* xb  = (unsigned short*)smem;
  unsigned short* xbT = (unsigned short*)(smem + 20480);
  unsigned short (*A_lds)[8][72] = (unsigned short (*)[8][72])(smem + 37376);

  const float4* xg4 =
      (const float4*)x + ((size_t)b * Pp + (size_t)yb * (ROUNDS * 256)) * 8;
  unsigned short* xnb =
      xn + ((size_t)b * Pp + (size_t)yb * (ROUNDS * 256)) * 32;
  float4 st[8];   // iter-1 only: raw f32 x prefetch (r8-identical structure)
  if (!ITER2) {
    #pragma unroll
    for (int i = 0; i < 8; ++i)     // round-0, coalesced (issued pre-preamble)
      st[i] = xg4[w * 512 + i * 64 + lane];
  }

  // LN gain/bias for this lane's 4 columns (iter-1 only)
  float4 lgv, lbv;
  if (!ITER2) {
    lgv = *(const float4*)&lg[c];
    lbv = *(const float4*)&lb[c];
  }

  short8 aq;
  if (!ITER2) {
    // ---- per-block q~ preamble (iter 1) ----
    float* wq  = (float*)smem;             // 64*65
    float* wk  = (float*)(smem + 16640);   // 64*33
    float* lnv = (float*)(smem + 25088);   // 8*64
    unsigned short* qtb = (unsigned short*)(smem + 27136);  // 16*32
    {
      const float4* g4 = (const float4*)Wq;
      #pragma unroll
      for (int i = 0; i < 4; ++i) {
        int f4i = threadIdx.x + i * 256;
        float4 v = g4[f4i];
        int fi = f4i * 4, row = fi >> 6, col = fi & 63;
        float* dst = &wq[row * 65 + col];
        dst[0] = v.x; dst[1] = v.y; dst[2] = v.z; dst[3] = v.w;
      }
      const float4* gk = (const float4*)Wk;
      #pragma unroll
      for (int i = 0; i < 2; ++i) {
        int f4i = threadIdx.x + i * 256;
        float4 v = gk[f4i];
        int fi = f4i * 4, row = fi >> 5, col = fi & 31;
        float* dst = &wk[row * 33 + col];
        dst[0] = v.x; dst[1] = v.y; dst[2] = v.z; dst[3] = v.w;
      }
    }
    const int j = lane;
    #pragma unroll
    for (int kk0 = 0; kk0 < 2; ++kk0) {
      const int kk = w + kk0 * 4;
      float s0 = smu[j] + fabsf(ssig[j]) * noise[((size_t)b * Kk + kk) * Dd + j];
      float mu  = wsum(s0) * (1.f / 64.f);
      float dc  = s0 - mu;
      float var = wsum(dc * dc) * (1.f / 64.f);
      lnv[kk * 64 + j] = dc * rsqrtf(var + EPS_LN_) * lsg[j] + lsb[j];
    }
    __syncthreads();
    float qa = 0.f, qb = 0.f;
    #pragma unroll 8
    for (int d = 0; d < Dd; ++d) {
      float wv = wq[j * 65 + d];
      qa = fmaf(wv, lnv[w * 64 + d],       qa);
      qb = fmaf(wv, lnv[(w + 4) * 64 + d], qb);
    }
    __syncthreads();
    lnv[w * 64 + j]       = qa * SCALE_;
    lnv[(w + 4) * 64 + j] = qb * SCALE_;
    __syncthreads();
    {
      const int kq = threadIdx.x >> 5, fq = threadIdx.x & 31;
      float qt = 0.f;
      #pragma unroll 8
      for (int d = 0; d < Dd; ++d) qt = fmaf(lnv[kq * 64 + d], wk[d * 33 + fq], qt);
      qtb[kq * 32 + fq]       = f2bf(qt);
      qtb[(kq + 8) * 32 + fq] = 0;           // zero rows 8..15 (MFMA M=16)
    }
    __syncthreads();
    aq = *(const short8*)&qtb[m * 32 + quad * 8];
    __syncthreads();   // qtb/lnv reads done before xb/xbT writes overwrite
  } else {
    aq = *(const short8*)(qt_bf + ((size_t)b * 16 + m) * Ff + quad * 8);
  }

  float Ss0 = 0.f, Ss1 = 0.f, Ss2 = 0.f, Ss3 = 0.f;
  floatx4 Cg0 = {0.f,0.f,0.f,0.f}, Cg1 = {0.f,0.f,0.f,0.f};

  #pragma unroll 1
  for (int rr = 0; rr < ROUNDS; ++rr) {
    // ---- produce (iter1: shuffle-LN + persist) / consume (iter2: load xn)
    #pragma unroll
    for (int i = 0; i < 8; ++i) {
      const int pxl = w * 64 + i * 8 + (lane >> 3);   // own pixel, own wave
      unsigned u0, u1;
      if (!ITER2) {
        float4 v = st[i];
        if (rr + 1 < ROUNDS)   // rotate prefetch into the just-freed slot
          st[i] = xg4[(rr + 1) * 2048 + w * 512 + i * 64 + lane];
        float s = (v.x + v.y) + (v.z + v.w);
        s += __shfl_xor(s, 1, 64);
        s += __shfl_xor(s, 2, 64);
        s += __shfl_xor(s, 4, 64);
        const float mu = s * (1.f / 32.f);
        const float d0 = v.x - mu, d1 = v.y - mu, d2 = v.z - mu, d3 = v.w - mu;
        float q = fmaf(d0, d0, fmaf(d1, d1, fmaf(d2, d2, d3 * d3)));
        q += __shfl_xor(q, 1, 64);
        q += __shfl_xor(q, 2, 64);
        q += __shfl_xor(q, 4, 64);
        const float rn = rsqrtf(q * (1.f / 32.f) + EPS_LN_);
        const float o0 = fmaf(d0 * rn, lgv.x, lbv.x);
        const float o1 = fmaf(d1 * rn, lgv.y, lbv.y);
        const float o2 = fmaf(d2 * rn, lgv.z, lbv.z);
        const float o3 = fmaf(d3 * rn, lgv.w, lbv.w);
        u0 = pkbf(o0, o1); u1 = pkbf(o2, o3);
        // persist LN'd bf16 x for iter-2 reuse (coalesced 512B/wave)
        *(uint2*)&xnb[(size_t)(rr * 256 + pxl) * 32 + c] = make_uint2(u0, u1);
      } else {
        // direct LLC-warm load; no prefetch array -> minimal reg pressure
        uint2 uv = *(const uint2*)&xnb[(size_t)(rr * 256 + pxl) * 32 + c];
        u0 = uv.x; u1 = uv.y;
      }
      *(uint2*)&xb[pxl * 40 + c] = make_uint2(u0, u1);
      xbT[(c + 0) * 264 + pxl] = (unsigned short)(u0 & 0xffffu);
      xbT[(c + 1) * 264 + pxl] = (unsigned short)(u0 >> 16);
      xbT[(c + 2) * 264 + pxl] = (unsigned short)(u1 & 0xffffu);
      xbT[(c + 3) * 264 + pxl] = (unsigned short)(u1 >> 16);
    }

    // ---- phase 1: dots + softmax over slots (reads wave-own xb rows)
    const int p0 = yb * (ROUNDS * 256) + rr * 256;
    #pragma unroll
    for (int t = 0; t < 4; ++t) {
      const int lpx = w * 64 + t * 16 + m;
      const short8 bx = *(const short8*)&xb[lpx * 40 + quad * 8];
      floatx4 C = {0.f, 0.f, 0.f, 0.f};
      C = __builtin_amdgcn_mfma_f32_16x16x32_bf16(aq, bx, C, 0, 0, 0);
      // C: col=m=pixel, row=quad*4+r=slot; slot pairs in lanes {l, l^16}
      float mx = fmaxf(fmaxf(C[0], C[1]), fmaxf(C[2], C[3]));
      mx = fmaxf(mx, __shfl_xor(mx, 16, 64));
      float e0 = __expf(C[0] - mx), e1 = __expf(C[1] - mx),
            e2 = __expf(C[2] - mx), e3 = __expf(C[3] - mx);
      float s = e0 + e1 + e2 + e3;
      s += __shfl_xor(s, 16, 64);
      float inv = 1.f / s;
      float a0 = fmaf(e0, inv, EPS_ATTN_), a1 = fmaf(e1, inv, EPS_ATTN_);
      float a2 = fmaf(e2, inv, EPS_ATTN_), a3 = fmaf(e3, inv, EPS_ATTN_);
      Ss0 += a0; Ss1 += a1; Ss2 += a2; Ss3 += a3;
      if (quad < 2) {                      // rows 0..7 are the real slots
        const int r0 = quad * 4;
        unsigned c01 = pkbf(a0, a1), c23 = pkbf(a2, a3);
        A_lds[w][r0 + 0][t * 16 + m] = (unsigned short)(c01 & 0xffffu);
        A_lds[w][r0 + 1][t * 16 + m] = (unsigned short)(c01 >> 16);
        A_lds[w][r0 + 2][t * 16 + m] = (unsigned short)(c23 & 0xffffu);
        A_lds[w][r0 + 3][t * 16 + m] = (unsigned short)(c23 >> 16);
      }
    }
    // ---- phase 2: acc[slot][f] += attn @ xn (reads wave-own A_lds/xbT)
    #pragma unroll
    for (int ks = 0; ks < 2; ++ks) {
      const short8 af = *(const short8*)(&A_lds[w][m & 7][ks * 32 + quad * 8]);
      const int pxo = w * 64 + ks * 32 + quad * 8;
      const short8 xg0 = *(const short8*)&xbT[(m)      * 264 + pxo];  // f = m
      const short8 xg1 = *(const short8*)&xbT[(16 + m) * 264 + pxo];  // f = 16+m
      Cg0 = __builtin_amdgcn_mfma_f32_16x16x32_bf16(af, xg0, Cg0, 0, 0, 0);
      Cg1 = __builtin_amdgcn_mfma_f32_16x16x32_bf16(af, xg1, Cg1, 0, 0, 0);
    }
    // ---- iter-2: coalesced dump of this round's unnormalized attn (bf16)
    if (ITER2) {
      const int sl = lane >> 3, p8 = (lane & 7) * 8;
      const short8 av = *(const short8*)&A_lds[w][sl][p8];
      *(short8*)(attn_bf + ((size_t)b * Kk + sl) * Pp + p0 + w * 64 + p8) = av;
    }
  }
  // ---- epilogue: per-wave private slices (slice id = yb*4 + w, 32 total)
  Ss0 += __shfl_xor(Ss0,1,64); Ss0 += __shfl_xor(Ss0,2,64); Ss0 += __shfl_xor(Ss0,4,64); Ss0 += __shfl_xor(Ss0,8,64);
  Ss1 += __shfl_xor(Ss1,1,64); Ss1 += __shfl_xor(Ss1,2,64); Ss1 += __shfl_xor(Ss1,4,64); Ss1 += __shfl_xor(Ss1,8,64);
  Ss2 += __shfl_xor(Ss2,1,64); Ss2 += __shfl_xor(Ss2,2,64); Ss2 += __shfl_xor(Ss2,4,64); Ss2 += __shfl_xor(Ss2,8,64);
  Ss3 += __shfl_xor(Ss3,1,64); Ss3 += __shfl_xor(Ss3,2,64); Ss3 += __shfl_xor(Ss3,4,64); Ss3 += __shfl_xor(Ss3,8,64);
  if (quad < 2) {
    const int row = quad * 4;
    const int slice = yb * 4 + w;            // 0..31
    float* tp = acc_tp + (size_t)b * (NSLICE * 256) + (size_t)slice * 256 +
                (size_t)row * 32 + m;
    #pragma unroll
    for (int r = 0; r < 4; ++r) {
      tp[r * 32]      = Cg0[r];
      tp[r * 32 + 16] = Cg1[r];
    }
    if (m == 0) {
      float* sp = Ssp + ((size_t)b * NSLICE + slice) * 8 + row;
      sp[0] = Ss0; sp[1] = Ss1; sp[2] = Ss2; sp[3] = Ss3;
    }
  }
}

__device__ __forceinline__ void stage_gate_pair(
    float* A, float* Bd, const float* Wih, const float* Whh, int g) {
  const float4* gi = (const float4*)Wih + (size_t)g * 1024;  // rows [64g,64g+64)
  const float4* gh = (const float4*)Whh + (size_t)g * 1024;
  #pragma unroll
  for (int i = 0; i < 4; ++i) {
    int f4i = threadIdx.x + i * 256;
    float4 vi = gi[f4i], vh = gh[f4i];
    int fi = f4i * 4, row = fi >> 6, col = fi & 63;
    float* da = &A[row * 65 + col];
    float* db = &Bd[row * 65 + col];
    da[0]=vi.x; da[1]=vi.y; da[2]=vi.z; da[3]=vi.w;
    db[0]=vh.x; db[1]=vh.y; db[2]=vh.z; db[3]=vh.w;
  }
}

// gru phase (device fn): weights staged sequentially per gate, 37376 B LDS.
// Verified correct in rounds 2-10.
template <bool LAST>
__device__ void gru_phase(
    char* smem,
    const float* __restrict__ acc_tp, const float* __restrict__ Ssp,
    float* __restrict__ slots,
    const float* __restrict__ noise, const float* __restrict__ smu,
    const float* __restrict__ ssig,
    const float* __restrict__ W_ih, const float* __restrict__ W_hh,
    const float* __restrict__ b_ih, const float* __restrict__ b_hh,
    const float* __restrict__ fg, const float* __restrict__ fb,
    const float* __restrict__ W1, const float* __restrict__ b1,
    const float* __restrict__ W2, const float* __restrict__ b2,
    const float* __restrict__ lsg, const float* __restrict__ lsb,
    const float* __restrict__ Wq, const float* __restrict__ Wv,
    const float* __restrict__ Wk,
    unsigned short* __restrict__ qt_bf, float* __restrict__ out_slots) {
  const int b  = blockIdx.x;
  const int kh = blockIdx.y;              // 0..1, slot half
  const int k  = threadIdx.x >> 6;        // local slot 0..3
  const int j  = threadIdx.x & 63;
  const int kg = kh * 4 + k;
  const size_t rk = (size_t)b * Kk + kg;
  float* WS0 = (float*)smem;              // staging (<= 33280 B)
  float* At  = (float*)(smem + 16640);    // C1 only
  float* WS1 = (float*)(smem + 16640);
  float* qs  = (float*)(smem + 16640);    // C7 only
  float* WKs = (float*)(smem + 17664);    // C7 only
  float* Ub  = (float*)(smem + 33280);    // [4][64]
  float* Hb  = (float*)(smem + 34304);    // [4][64]
  float* Tb  = (float*)(smem + 35328);    // [4][128], ends 37376

  // ---- C1: Wv stage; S & At sums; h; u = (T @ Wv^T)/S
  {
    const float4* gv = (const float4*)Wv;
    #pragma unroll
    for (int i = 0; i < 2; ++i) {
      int f4i = threadIdx.x + i * 256;
      float4 v = gv[f4i];
      int fi = f4i * 4, row = fi >> 5, col = fi & 31;
      float* d_ = &WS0[row * 33 + col];
      d_[0]=v.x; d_[1]=v.y; d_[2]=v.z; d_[3]=v.w;
    }
  }
  float S = 0.f;
  #pragma unroll
  for (int y2 = 0; y2 < NSLICE; ++y2) S += Ssp[((size_t)b * NSLICE + y2) * 8 + kg];
  if (j < Ff) {
    const float* tp = acc_tp + (size_t)b * (NSLICE * 256) + (size_t)kg * 32 + j;
    float t = 0.f;
    #pragma unroll
    for (int y2 = 0; y2 < NSLICE; ++y2) t += tp[y2 * 256];
    At[k * Ff + j] = t;
  }
  float h;
  if (LAST) h = slots[rk * Dd + j];
  else      h = smu[j] + fabsf(ssig[j]) * noise[rk * Dd + j];  // slots0
  Hb[k * Dd + j] = h;
  __syncthreads();
  float u = 0.f;
  #pragma unroll 8
  for (int f = 0; f < Ff; ++f) u = fmaf(WS0[j * 33 + f], At[k * Ff + f], u);
  u /= S;
  Ub[k * Dd + j] = u;
  __syncthreads();

  // ---- C2..C4: gates r,z,n staged one at a time
  float gr, hr, gz, hz, gn, hn_;
  stage_gate_pair(WS0, WS1, W_ih, W_hh, 0);
  __syncthreads();
  gr = b_ih[j]; hr = b_hh[j];
  #pragma unroll 4
  for (int d = 0; d < Dd; ++d) {
    gr = fmaf(WS0[j * 65 + d], Ub[k * Dd + d], gr);
    hr = fmaf(WS1[j * 65 + d], Hb[k * Dd + d], hr);
  }
  __syncthreads();
  stage_gate_pair(WS0, WS1, W_ih, W_hh, 1);
  __syncthreads();
  gz = b_ih[64 + j]; hz = b_hh[64 + j];
  #pragma unroll 4
  for (int d = 0; d < Dd; ++d) {
    gz = fmaf(WS0[j * 65 + d], Ub[k * Dd + d], gz);
    hz = fmaf(WS1[j * 65 + d], Hb[k * Dd + d], hz);
  }
  __syncthreads();
  stage_gate_pair(WS0, WS1, W_ih, W_hh, 2);
  __syncthreads();
  gn = b_ih[128 + j]; hn_ = b_hh[128 + j];
  #pragma unroll 4
  for (int d = 0; d < Dd; ++d) {
    gn  = fmaf(WS0[j * 65 + d], Ub[k * Dd + d], gn);
    hn_ = fmaf(WS1[j * 65 + d], Hb[k * Dd + d], hn_);
  }
  const float r = 1.f / (1.f + __expf(-(gr + hr)));
  const float z = 1.f / (1.f + __expf(-(gz + hz)));
  const float n = tanhf(fmaf(r, hn_, gn));
  const float hnew = fmaf(z, h - n, n);    // (1-z)*n + z*h
  float mu  = wsum(hnew) * (1.f / 64.f);
  float dc  = hnew - mu;
  float var = wsum(dc * dc) * (1.f / 64.f);
  float fi_ = dc * rsqrtf(var + EPS_LN_) * fg[j] + fb[j];
  __syncthreads();   // all gate reads of WS0/WS1/Ub done
  Ub[k * Dd + j] = fi_;
  // ---- C5: W1 (128x65)
  {
    const float4* g1 = (const float4*)W1;
    #pragma unroll
    for (int i = 0; i < 8; ++i) {
      int f4i = threadIdx.x + i * 256;
      float4 v = g1[f4i];
      int fi = f4i * 4, row = fi >> 6, col = fi & 63;
      float* d_ = &WS0[row * 65 + col];
      d_[0]=v.x; d_[1]=v.y; d_[2]=v.z; d_[3]=v.w;
    }
  }
  __syncthreads();
  float f1a = b1[j], f1b = b1[64 + j];
  #pragma unroll 4
  for (int d = 0; d < Dd; ++d) {
    const float t = Ub[k * Dd + d];
    f1a = fmaf(WS0[j * 65 + d],        t, f1a);
    f1b = fmaf(WS0[(64 + j) * 65 + d], t, f1b);
  }
  f1a = fmaxf(f1a, 0.f);
  f1b = fmaxf(f1b, 0.f);
  Tb[k * 128 + j]      = f1a;
  Tb[k * 128 + 64 + j] = f1b;
  __syncthreads();
  // ---- C6: W2 (64x129)
  {
    const float4* g2 = (const float4*)W2;
    #pragma unroll
    for (int i = 0; i < 8; ++i) {
      int f4i = threadIdx.x + i * 256;
      float4 v = g2[f4i];
      int fi = f4i * 4, row = fi >> 7, col = fi & 127;
      float* d_ = &WS0[row * 129 + col];
      d_[0]=v.x; d_[1]=v.y; d_[2]=v.z; d_[3]=v.w;
    }
  }
  __syncthreads();
  float o = b2[j];
  #pragma unroll 4
  for (int e = 0; e < 2 * Dd; ++e) o = fmaf(WS0[j * 129 + e], Tb[k * 128 + e], o);
  const float sn = hnew + o;
  if (!LAST) {
    slots[rk * Dd + j] = sn;
    float mq = wsum(sn) * (1.f / 64.f);
    float dq = sn - mq;
    float vq = wsum(dq * dq) * (1.f / 64.f);
    float xq = dq * rsqrtf(vq + EPS_LN_) * lsg[j] + lsb[j];
    __syncthreads();          // W2/Tb reads done before restage / Ub rewrite
    Ub[k * Dd + j] = xq;
    // ---- C7: Wq + Wk -> q~ for iter 2
    {
      const float4* gq = (const float4*)Wq;
      #pragma unroll
      for (int i = 0; i < 4; ++i) {
        int f4i = threadIdx.x + i * 256;
        float4 v = gq[f4i];
        int fi = f4i * 4, row = fi >> 6, col = fi & 63;
        float* d_ = &WS0[row * 65 + col];
        d_[0]=v.x; d_[1]=v.y; d_[2]=v.z; d_[3]=v.w;
      }
      const float4* gk2 = (const float4*)Wk;
      #pragma unroll
      for (int i = 0; i < 2; ++i) {
        int f4i = threadIdx.x + i * 256;
        float4 v = gk2[f4i];
        int fi = f4i * 4, row = fi >> 5, col = fi & 31;
        float* d_ = &WKs[row * 33 + col];
        d_[0]=v.x; d_[1]=v.y; d_[2]=v.z; d_[3]=v.w;
      }
    }
    __syncthreads();
    float q = 0.f;
    #pragma unroll 8
    for (int d = 0; d < Dd; ++d) q = fmaf(WS0[j * 65 + d], Ub[k * Dd + d], q);
    qs[k * Dd + j] = q * SCALE_;
    __syncthreads();
    if (j < Ff) {
      float qt = 0.f;
      #pragma unroll 8
      for (int d = 0; d < Dd; ++d) qt = fmaf(qs[k * Dd + d], WKs[d * 33 + j], qt);
      qt_bf[((size_t)b * 16 + kg) * Ff + j]     = f2bf(qt);
      qt_bf[((size_t)b * 16 + kg + 8) * Ff + j] = 0;
    }
  } else {
    out_slots[rk * Dd + j] = sn;
  }
}

__global__ __launch_bounds__(256) void gru1_kernel(
    const float* __restrict__ acc_tp, const float* __restrict__ Ssp,
    float* __restrict__ slots,
    const float* __restrict__ noise, const float* __restrict__ smu,
    const float* __restrict__ ssig,
    const float* __restrict__ W_ih, const float* __restrict__ W_hh,
    const float* __restrict__ b_ih, const float* __restrict__ b_hh,
    const float* __restrict__ fg, const float* __restrict__ fb,
    const float* __restrict__ W1, const float* __restrict__ b1,
    const float* __restrict__ W2, const float* __restrict__ b2,
    const float* __restrict__ lsg, const float* __restrict__ lsb,
    const float* __restrict__ Wq, const float* __restrict__ Wv,
    const float* __restrict__ Wk, unsigned short* __restrict__ qt_bf) {
  __shared__ __align__(16) char smem[37376];
  gru_phase<false>(smem, acc_tp, Ssp, slots, noise, smu, ssig, W_ih, W_hh,
                   b_ih, b_hh, fg, fb, W1, b1, W2, b2, lsg, lsb, Wq, Wv, Wk,
                   qt_bf, nullptr);
}

// grid (128,18): yb<2 -> gru iter2 (-> out_slots); yb in [2,18) -> normalize
// strip (yb-2) of out_attn (256 px x 8 slots) from bf16 attn_bf and 1/S.
__global__ __launch_bounds__(256) void gru2_scale_kernel(
    const float* __restrict__ acc_tp, const float* __restrict__ Ssp,
    float* __restrict__ slots,
    const float* __restrict__ noise, const float* __restrict__ smu,
    const float* __restrict__ ssig,
    const float* __restrict__ W_ih, const float* __restrict__ W_hh,
    const float* __restrict__ b_ih, const float* __restrict__ b_hh,
    const float* __restrict__ fg, const float* __restrict__ fb,
    const float* __restrict__ W1, const float* __restrict__ b1,
    const float* __restrict__ W2, const float* __restrict__ b2,
    const float* __restrict__ lsg, const float* __restrict__ lsb,
    const float* __restrict__ Wq, const float* __restrict__ Wv,
    const float* __restrict__ Wk,
    const unsigned short* __restrict__ attn_bf,
    float* __restrict__ out_slots, float* __restrict__ out_attn) {
  __shared__ __align__(16) char smem[37376];
  if (blockIdx.y < 2) {
    gru_phase<true>(smem, acc_tp, Ssp, slots, noise, smu, ssig, W_ih, W_hh,
                    b_ih, b_hh, fg, fb, W1, b1, W2, b2, lsg, lsb, Wq, Wv, Wk,
                    nullptr, out_slots);
  } else {
    const int b = blockIdx.x;
    const int s = blockIdx.y - 2;           // strip 0..15 (256 px each)
    float* Sbuf = (float*)smem;
    if (threadIdx.x < 8) {
      float S = 0.f;
      #pragma unroll
      for (int y2 = 0; y2 < NSLICE; ++y2)
        S += Ssp[((size_t)b * NSLICE + y2) * 8 + threadIdx.x];
      Sbuf[threadIdx.x] = 1.f / S;
    }
    __syncthreads();
    #pragma unroll
    for (int i = 0; i < 2; ++i) {
      int g = threadIdx.x + i * 256;        // 0..511
      int slot = g >> 6;                    // 0..7
      int px4 = (g & 63) * 4;               // 0..252
      size_t off = ((size_t)b * Kk + slot) * Pp + (size_t)s * 256 + px4;
      uint2 v = *(const uint2*)(attn_bf + off);
      float inv = Sbuf[slot];
      float4 ov;
      ov.x = bf2f(v.x & 0xffffu) * inv;
      ov.y = bf2f(v.x >> 16)     * inv;
      ov.z = bf2f(v.y & 0xffffu) * inv;
      ov.w = bf2f(v.y >> 16)     * inv;
      *(float4*)(out_attn + off) = ov;
    }
  }
}

extern "C" void kernel_launch(void* const* d_in, const int* in_sizes, int n_in,
                              void* d_out, int out_size, void* d_ws, size_t ws_size,
                              hipStream_t stream) {
  const float* x      = (const float*)d_in[0];
  const float* noise  = (const float*)d_in[1];
  const float* smu    = (const float*)d_in[2];
  const float* ssig   = (const float*)d_in[3];
  const float* Wq     = (const float*)d_in[4];
  const float* Wk     = (const float*)d_in[5];
  const float* Wv     = (const float*)d_in[6];
  const float* W_ih   = (const float*)d_in[7];
  const float* W_hh   = (const float*)d_in[8];
  const float* b_ih   = (const float*)d_in[9];
  const float* b_hh   = (const float*)d_in[10];
  const float* ln_in_g = (const float*)d_in[11];
  const float* ln_in_b = (const float*)d_in[12];
  const float* ln_s_g  = (const float*)d_in[13];
  const float* ln_s_b  = (const float*)d_in[14];
  const float* ff_g   = (const float*)d_in[15];
  const float* ff_b   = (const float*)d_in[16];
  const float* W1     = (const float*)d_in[17];
  const float* b1     = (const float*)d_in[18];
  const float* W2     = (const float*)d_in[19];
  const float* b2     = (const float*)d_in[20];

  char* ws = (char*)d_ws;
  unsigned short* qt_bf = (unsigned short*)(ws);             //    131,072 B
  float* slots   = (float*)(ws + 131072);                    //    262,144 B
  float* acc_tp  = (float*)(ws + 393216);                    //  4,194,304 B [B][32][8][32]
  float* Ssp     = (float*)(ws + 4587520);                   //    131,072 B [B][32][8]
  unsigned short* attn_bf = (unsigned short*)(ws + 4718592); //  8,388,608 B [B][K][P]
  unsigned short* xn      = (unsigned short*)(ws + 13107200);// 33,554,432 B [B][P][F] bf16

  float* out_slots = (float*)d_out;                          // [B,K,D] f32
  float* out_attn  = out_slots + (size_t)Bb * Kk * Dd;       // [B,K,P] f32

  fattn_kernel<false><<<dim3(Bb, 8), dim3(256), 0, stream>>>(
      x, nullptr, ln_in_g, ln_in_b, noise, smu, ssig, Wq, Wk, ln_s_g, ln_s_b,
      acc_tp, Ssp, nullptr, xn);
  gru1_kernel<<<dim3(Bb, 2), dim3(256), 0, stream>>>(
      acc_tp, Ssp, slots, noise, smu, ssig, W_ih, W_hh, b_ih, b_hh, ff_g, ff_b,
      W1, b1, W2, b2, ln_s_g, ln_s_b, Wq, Wv, Wk, qt_bf);
  fattn_kernel<true><<<dim3(Bb, 8), dim3(256), 0, stream>>>(
      x, qt_bf, ln_in_g, ln_in_b, nullptr, nullptr, nullptr, nullptr, nullptr,
      nullptr, nullptr, acc_tp, Ssp, attn_bf, xn);
  gru2_scale_kernel<<<dim3(Bb, 18), dim3(256), 0, stream>>>(
      acc_tp, Ssp, slots, noise, smu, ssig, W_ih, W_hh, b_ih, b_hh, ff_g, ff_b,
      W1, b1, W2, b2, ln_s_g, ln_s_b, Wq, Wv, Wk, attn_bf, out_slots, out_attn);
}